// Round 6
// baseline (770.616 us; speedup 1.0000x reference)
//
#include <hip/hip_runtime.h>
#include <hip/hip_fp16.h>
#include <cstdint>

#define HD    128
#define OUTD  10
#define NG    512
#define KSTEPS 10

typedef unsigned short ushort_t;
typedef unsigned int   uint_t;
typedef unsigned char  uchar_t;

// bf16 helpers (stored as ushort; f32 accumulate everywhere)
__device__ __forceinline__ float bf_lo(uint_t u) { return __uint_as_float(u << 16); }
__device__ __forceinline__ float bf_hi(uint_t u) { return __uint_as_float(u & 0xFFFF0000u); }
__device__ __forceinline__ uint_t f2bf_rne(float f) {          // 16-bit result
    uint_t u = __float_as_uint(f);
    return (u + 0x7FFFu + ((u >> 16) & 1u)) >> 16;
}
__device__ __forceinline__ uint_t pack_bf2(float lo, float hi) {
    return f2bf_rne(lo) | (f2bf_rne(hi) << 16);
}

// ---------------------------------------------------------------------------
// 1) Collapse the two linear layers: Wc = W1@W2, bc = b1@W2 + b2
// ---------------------------------------------------------------------------
__global__ void wc_kernel(const float* __restrict__ W1, const float* __restrict__ b1,
                          const float* __restrict__ W2, const float* __restrict__ b2,
                          float* __restrict__ Wc, float* __restrict__ bc) {
    int idx = blockIdx.x * 256 + threadIdx.x;      // 0..16383
    int d = idx >> 7, j = idx & 127;
    float s = 0.f;
    for (int t = 0; t < HD; t++) s += W1[d * HD + t] * W2[t * HD + j];
    Wc[idx] = s;
    if (idx < HD) {
        float sb = b2[idx];
        for (int t = 0; t < HD; t++) sb += b1[t] * W2[t * HD + idx];
        bc[idx] = sb;
    }
}

// ---------------------------------------------------------------------------
// 2) h[n][j] = sum_d feat[d][n] * Wc[d][j] + bc[j]  -> stored bf16 [N][128]
// ---------------------------------------------------------------------------
__global__ void __launch_bounds__(256) feat_kernel(
        const float* __restrict__ feat, const float* __restrict__ Wc,
        const float* __restrict__ bc, ushort_t* __restrict__ h, int N) {
    __shared__ float ftile[HD][16];
    int tid = threadIdx.x;
    int n0 = blockIdx.x * 16;
    #pragma unroll
    for (int r = 0; r < 8; r++) {
        int l = tid * 8 + r;
        int d = l >> 4, n = l & 15;
        int nn = n0 + n;
        ftile[d][n] = (nn < N) ? feat[(size_t)d * N + nn] : 0.f;
    }
    __syncthreads();
    int j = tid & 127, half = tid >> 7;
    float acc[8];
    #pragma unroll
    for (int i = 0; i < 8; i++) acc[i] = 0.f;
    for (int d = 0; d < HD; d++) {
        float w = Wc[d * HD + j];
        #pragma unroll
        for (int i = 0; i < 8; i++) acc[i] += ftile[d][half * 8 + i] * w;
    }
    float bb = bc[j];
    #pragma unroll
    for (int i = 0; i < 8; i++) {
        int n = n0 + half * 8 + i;
        if (n < N) h[(size_t)n * HD + j] = (ushort_t)f2bf_rne(acc[i] + bb);
    }
}

// ---------------------------------------------------------------------------
// 3) CSR build via two-level bucket sort (NO global per-node atomics).
// ---------------------------------------------------------------------------

// S1: global bucket sizes (LDS hist, then one atomic per nonzero bucket/block)
__global__ void __launch_bounds__(256) bcount_kernel(
        const int* __restrict__ ei, int* __restrict__ gbhist, int E, int chunk) {
    __shared__ int lh[256];
    int b = blockIdx.x, t = threadIdx.x;
    lh[t] = 0;
    __syncthreads();
    int lo = b * chunk, hi = min(E, lo + chunk);
    for (int i = lo + t; i < hi; i += 256) atomicAdd(&lh[ei[E + i] >> 8], 1);
    __syncthreads();
    if (lh[t]) atomicAdd(&gbhist[t], lh[t]);
}

// S2: exclusive scan of bucket sizes -> bucket_base[0..NBK], bcursor init
__global__ void bscan_kernel(const int* __restrict__ gbhist, int* __restrict__ bucket_base,
                             int* __restrict__ bcursor, int NBK, int E) {
    __shared__ int sm[256];
    int t = threadIdx.x;
    int v = (t < NBK) ? gbhist[t] : 0;
    sm[t] = v;
    __syncthreads();
    for (int off = 1; off < 256; off <<= 1) {
        int u = (t >= off) ? sm[t - off] : 0;
        __syncthreads();
        sm[t] += u;
        __syncthreads();
    }
    int excl = sm[t] - v;
    if (t < NBK) { bucket_base[t] = excl; bcursor[t] = excl; }
    if (t == 0) bucket_base[NBK] = E;
}

// S3: scatter edges into bucket-ordered intermediate (rec + low-byte of dst).
__global__ void __launch_bounds__(256) bscatter_kernel(
        const int* __restrict__ ei, const float* __restrict__ ewt,
        int* __restrict__ bcursor, uint_t* __restrict__ rec_tmp,
        uchar_t* __restrict__ dlo_tmp, int E, int chunk) {
    __shared__ int lh[256];
    __shared__ int lcur[256];
    int b = blockIdx.x, t = threadIdx.x;
    lh[t] = 0;
    __syncthreads();
    int lo = b * chunk, hi = min(E, lo + chunk);
    for (int i = lo + t; i < hi; i += 256) atomicAdd(&lh[ei[E + i] >> 8], 1);
    __syncthreads();
    lcur[t] = lh[t] ? atomicAdd(&bcursor[t], lh[t]) : 0;
    __syncthreads();
    for (int i = lo + t; i < hi; i += 256) {
        int d = ei[E + i];
        int p = atomicAdd(&lcur[d >> 8], 1);
        rec_tmp[p] = ((uint_t)ei[i] << 16) |
                     (uint_t)__half_as_ushort(__float2half(ewt[i]));
        dlo_tmp[p] = (uchar_t)(d & 255);
    }
}

// S4: within-bucket counting sort by dst&255 (all in LDS); emit row_ptr+erec.
__global__ void __launch_bounds__(256) bsort_kernel(
        const uint_t* __restrict__ rec_tmp, const uchar_t* __restrict__ dlo_tmp,
        const int* __restrict__ bucket_base, int* __restrict__ row_ptr,
        uint_t* __restrict__ erec, int N, int E) {
    __shared__ int hist[256];
    __shared__ int scn[256];
    __shared__ int cur[256];
    int b = blockIdx.x, t = threadIdx.x;
    int lo = bucket_base[b], hi = bucket_base[b + 1];
    hist[t] = 0;
    __syncthreads();
    for (int i = lo + t; i < hi; i += 256) atomicAdd(&hist[dlo_tmp[i]], 1);
    __syncthreads();
    int v = hist[t];
    scn[t] = v;
    __syncthreads();
    for (int off = 1; off < 256; off <<= 1) {
        int u = (t >= off) ? scn[t - off] : 0;
        __syncthreads();
        scn[t] += u;
        __syncthreads();
    }
    int excl = lo + scn[t] - v;
    int node = (b << 8) + t;
    if (node < N) row_ptr[node] = excl;
    if (b == 0 && t == 0) row_ptr[N] = E;
    cur[t] = excl;
    __syncthreads();
    for (int i = lo + t; i < hi; i += 256) {
        int p = atomicAdd(&cur[dlo_tmp[i]], 1);
        erec[p] = rec_tmp[i];
    }
}

// ---------------------------------------------------------------------------
// 3b) Degree-class node permutation: counting-sort node ids by deg>>5
//     (= prop inner-loop iteration count) so co-scheduled waves have equal
//     trip counts. Poisson(32) degrees make ~92% of naive 4-wave blocks pay
//     a 2nd, mostly-masked 32-edge iteration; class-sorted assignment
//     removes that quantization tax. Order within a class is arbitrary.
// ---------------------------------------------------------------------------
__device__ __forceinline__ int deg_class(const int* __restrict__ row_ptr, int i) {
    return min((row_ptr[i + 1] - row_ptr[i]) >> 5, 255);
}

// P1: class histogram (LDS, then one global atomic per nonzero class/block)
__global__ void __launch_bounds__(256) chist_kernel(
        const int* __restrict__ row_ptr, int* __restrict__ chist, int N, int chunk) {
    __shared__ int lh[256];
    int b = blockIdx.x, t = threadIdx.x;
    lh[t] = 0;
    __syncthreads();
    int lo = b * chunk, hi = min(N, lo + chunk);
    for (int i = lo + t; i < hi; i += 256) atomicAdd(&lh[deg_class(row_ptr, i)], 1);
    __syncthreads();
    if (lh[t]) atomicAdd(&chist[t], lh[t]);
}

// P2: exclusive scan of class counts -> ccur (cursor init)
__global__ void cscan_kernel(const int* __restrict__ chist, int* __restrict__ ccur) {
    __shared__ int sm[256];
    int t = threadIdx.x;
    int v = chist[t];
    sm[t] = v;
    __syncthreads();
    for (int off = 1; off < 256; off <<= 1) {
        int u = (t >= off) ? sm[t - off] : 0;
        __syncthreads();
        sm[t] += u;
        __syncthreads();
    }
    ccur[t] = sm[t] - v;   // exclusive
}

// P3: place node ids (LDS hist + one reservation atomic per class/block)
__global__ void __launch_bounds__(256) cplace_kernel(
        const int* __restrict__ row_ptr, int* __restrict__ ccur,
        int* __restrict__ perm, int N, int chunk) {
    __shared__ int lh[256];
    __shared__ int lcur[256];
    int b = blockIdx.x, t = threadIdx.x;
    lh[t] = 0;
    __syncthreads();
    int lo = b * chunk, hi = min(N, lo + chunk);
    for (int i = lo + t; i < hi; i += 256) atomicAdd(&lh[deg_class(row_ptr, i)], 1);
    __syncthreads();
    lcur[t] = lh[t] ? atomicAdd(&ccur[t], lh[t]) : 0;
    __syncthreads();
    for (int i = lo + t; i < hi; i += 256) {
        int p = atomicAdd(&lcur[deg_class(row_ptr, i)], 1);
        perm[p] = i;
    }
}

// ---------------------------------------------------------------------------
// 4) APPNP step (bf16 rows): wave per dst node (via degree-class perm);
//    4 groups x 16 lanes; each group owns one edge, reads the 256B bf16 row
//    as one uint4 per lane. 8x unroll + 8-record prefetch. Tail slots use
//    clamped record 0 (src=0, w=0): cache-broadcast hits, ~free.
//    (R3: guards + nt loads both regress.) f32 acc, bf16-RNE out.
// ---------------------------------------------------------------------------
__global__ void __launch_bounds__(256) prop_kernel(
        const ushort_t* __restrict__ xs, ushort_t* __restrict__ xd,
        const ushort_t* __restrict__ h, const int* __restrict__ row_ptr,
        const uint_t* __restrict__ erec, const int* __restrict__ perm, int N) {
    int wid = threadIdx.x >> 6, lane = threadIdx.x & 63;
    int idx = blockIdx.x * 4 + wid;
    if (idx >= N) return;
    int node = perm[idx];
    int rs = row_ptr[node], re = row_ptr[node + 1];
    int grp = lane >> 4;        // edge slot 0..3
    int sub = lane & 15;        // dim slot: bf16 elems sub*8 .. sub*8+7

    float acc[8];
    #pragma unroll
    for (int i = 0; i < 8; i++) acc[i] = 0.f;

    uint_t p[8];
    #pragma unroll
    for (int u = 0; u < 8; u++) {
        int e = rs + grp + 4 * u;
        p[u] = (e < re) ? erec[e] : 0u;      // src=0, w=+0.0h
    }

    for (int base = rs; base < re; base += 32) {
        // prefetch next iteration's edge records
        uint_t q[8];
        #pragma unroll
        for (int u = 0; u < 8; u++) {
            int e = base + 32 + grp + 4 * u;
            q[u] = (e < re) ? erec[e] : 0u;
        }
        // 8 independent row gathers in flight (tail slots hit row 0, w=0)
        #pragma unroll
        for (int u = 0; u < 8; u++) {
            int   s = (int)(p[u] >> 16);
            float w = __half2float(__ushort_as_half((ushort_t)(p[u] & 0xFFFFu)));
            uint4 a = ((const uint4*)(xs + (size_t)s * HD))[sub];
            acc[0] += w * bf_lo(a.x); acc[1] += w * bf_hi(a.x);
            acc[2] += w * bf_lo(a.y); acc[3] += w * bf_hi(a.y);
            acc[4] += w * bf_lo(a.z); acc[5] += w * bf_hi(a.z);
            acc[6] += w * bf_lo(a.w); acc[7] += w * bf_hi(a.w);
        }
        #pragma unroll
        for (int u = 0; u < 8; u++) p[u] = q[u];
    }

    // reduce across the 4 edge groups
    #pragma unroll
    for (int off = 32; off >= 16; off >>= 1) {
        #pragma unroll
        for (int i = 0; i < 8; i++) acc[i] += __shfl_down(acc[i], off);
    }

    if (grp == 0) {
        uint4 hv = ((const uint4*)(h + (size_t)node * HD))[sub];
        float hf[8];
        hf[0] = bf_lo(hv.x); hf[1] = bf_hi(hv.x);
        hf[2] = bf_lo(hv.y); hf[3] = bf_hi(hv.y);
        hf[4] = bf_lo(hv.z); hf[5] = bf_hi(hv.z);
        hf[6] = bf_lo(hv.w); hf[7] = bf_hi(hv.w);
        float o[8];
        #pragma unroll
        for (int i = 0; i < 8; i++) o[i] = 0.9f * acc[i] + 0.1f * hf[i];
        uint4 ov;
        ov.x = pack_bf2(o[0], o[1]);
        ov.y = pack_bf2(o[2], o[3]);
        ov.z = pack_bf2(o[4], o[5]);
        ov.w = pack_bf2(o[6], o[7]);
        ((uint4*)(xd + (size_t)node * HD))[sub] = ov;
    }
}

// ---------------------------------------------------------------------------
// 5) Pool: batch is sorted -> running accumulator, atomic only on boundary.
// ---------------------------------------------------------------------------
#define POOL_CHUNK 128
__global__ void pool_kernel(const ushort_t* __restrict__ x, const int* __restrict__ batch,
                            float* __restrict__ pooled, int N) {
    int j = threadIdx.x;
    int n0 = blockIdx.x * POOL_CHUNK;
    if (n0 >= N) return;
    int n1 = min(n0 + POOL_CHUNK, N);
    int cur = batch[n0];
    float acc = 0.f;
    for (int n = n0; n < n1; n++) {
        int g = batch[n];
        if (g != cur) {
            atomicAdd(&pooled[cur * HD + j], acc);
            acc = 0.f; cur = g;
        }
        acc += __uint_as_float(((uint_t)x[(size_t)n * HD + j]) << 16);
    }
    atomicAdd(&pooled[cur * HD + j], acc);
}

// ---------------------------------------------------------------------------
// 6) Head: y = log_softmax(relu(pooled@V0w+V0b) @ V1w + V1b). Block per graph.
// ---------------------------------------------------------------------------
__global__ void head_kernel(const float* __restrict__ pooled, const float* __restrict__ V0w,
                            const float* __restrict__ V0b, const float* __restrict__ V1w,
                            const float* __restrict__ V1b, float* __restrict__ out) {
    __shared__ float prow[HD];
    __shared__ float y1[HD];
    __shared__ float y2[OUTD];
    __shared__ float lse;
    int g = blockIdx.x, j = threadIdx.x;
    prow[j] = pooled[g * HD + j];
    __syncthreads();
    float a = V0b[j];
    for (int d = 0; d < HD; d++) a += prow[d] * V0w[d * HD + j];
    y1[j] = a > 0.f ? a : 0.f;
    __syncthreads();
    if (j < OUTD) {
        float a2 = V1b[j];
        for (int t = 0; t < HD; t++) a2 += y1[t] * V1w[t * OUTD + j];
        y2[j] = a2;
    }
    __syncthreads();
    if (j == 0) {
        float m = y2[0];
        for (int o = 1; o < OUTD; o++) m = fmaxf(m, y2[o]);
        float s = 0.f;
        for (int o = 0; o < OUTD; o++) s += expf(y2[o] - m);
        lse = m + logf(s);
    }
    __syncthreads();
    if (j < OUTD) out[g * OUTD + j] = y2[j] - lse;
}

// ---------------------------------------------------------------------------
extern "C" void kernel_launch(void* const* d_in, const int* in_sizes, int n_in,
                              void* d_out, int out_size, void* d_ws, size_t ws_size,
                              hipStream_t stream) {
    const float* feat = (const float*)d_in[0];
    const float* ewt  = (const float*)d_in[1];
    const float* W1   = (const float*)d_in[2];
    const float* b1   = (const float*)d_in[3];
    const float* W2   = (const float*)d_in[4];
    const float* b2   = (const float*)d_in[5];
    const float* V0w  = (const float*)d_in[6];
    const float* V0b  = (const float*)d_in[7];
    const float* V1w  = (const float*)d_in[8];
    const float* V1b  = (const float*)d_in[9];
    const int*   ei   = (const int*)d_in[10];
    const int*   batch= (const int*)d_in[11];
    const int E = in_sizes[1];
    const int N = in_sizes[11];
    float* out = (float*)d_out;

    char* ws = (char*)d_ws;
    size_t off = 0;
    auto alloc = [&](size_t bytes) -> char* {
        char* p = ws + off;
        off = (off + bytes + 255) & ~(size_t)255;
        return p;
    };
    float*    Wc        = (float*)alloc((size_t)HD * HD * 4);
    float*    bc        = (float*)alloc((size_t)HD * 4);
    ushort_t* hb        = (ushort_t*)alloc((size_t)N * HD * 2);
    ushort_t* xA        = (ushort_t*)alloc((size_t)N * HD * 2);
    ushort_t* xB        = (ushort_t*)alloc((size_t)N * HD * 2);
    float*    pooled    = (float*)alloc((size_t)NG * HD * 4);
    int*      row_ptr   = (int*)alloc((size_t)(N + 1) * 4);
    int*      gbhist    = (int*)alloc((size_t)256 * 4);
    int*      bucket_b  = (int*)alloc((size_t)257 * 4);
    int*      bcursor   = (int*)alloc((size_t)256 * 4);
    int*      chist     = (int*)alloc((size_t)256 * 4);
    int*      ccur      = (int*)alloc((size_t)256 * 4);
    int*      perm      = (int*)alloc((size_t)N * 4);
    uint_t*   rec_tmp   = (uint_t*)alloc((size_t)E * 4);
    uchar_t*  dlo_tmp   = (uchar_t*)alloc((size_t)E);
    uint_t*   erec      = (uint_t*)alloc((size_t)E * 4);
    (void)ws_size;

    hipMemsetAsync(gbhist, 0, (size_t)256 * 4, stream);
    hipMemsetAsync(chist, 0, (size_t)256 * 4, stream);
    hipMemsetAsync(pooled, 0, (size_t)NG * HD * 4, stream);

    const int NBK    = (N + 255) >> 8;          // dst buckets (<=256 for N<65536)
    const int SBLK   = 256;                     // edge scatter blocks
    const int chunk  = (E + SBLK - 1) / SBLK;   // edges per scatter block
    const int PBLK   = 128;                     // perm-sort blocks
    const int chunkN = (N + PBLK - 1) / PBLK;   // nodes per perm block

    wc_kernel<<<64, 256, 0, stream>>>(W1, b1, W2, b2, Wc, bc);
    feat_kernel<<<(N + 15) / 16, 256, 0, stream>>>(feat, Wc, bc, hb, N);
    bcount_kernel<<<SBLK, 256, 0, stream>>>(ei, gbhist, E, chunk);
    bscan_kernel<<<1, 256, 0, stream>>>(gbhist, bucket_b, bcursor, NBK, E);
    bscatter_kernel<<<SBLK, 256, 0, stream>>>(ei, ewt, bcursor, rec_tmp, dlo_tmp, E, chunk);
    bsort_kernel<<<NBK, 256, 0, stream>>>(rec_tmp, dlo_tmp, bucket_b, row_ptr, erec, N, E);
    chist_kernel<<<PBLK, 256, 0, stream>>>(row_ptr, chist, N, chunkN);
    cscan_kernel<<<1, 256, 0, stream>>>(chist, ccur);
    cplace_kernel<<<PBLK, 256, 0, stream>>>(row_ptr, ccur, perm, N, chunkN);

    const ushort_t* src = hb;
    ushort_t* dst = xA;
    for (int k = 0; k < KSTEPS; k++) {
        prop_kernel<<<(N + 3) / 4, 256, 0, stream>>>(src, dst, hb, row_ptr, erec, perm, N);
        src = dst;
        dst = (dst == xA) ? xB : xA;
    }

    pool_kernel<<<(N + POOL_CHUNK - 1) / POOL_CHUNK, HD, 0, stream>>>(src, batch, pooled, N);
    head_kernel<<<NG, HD, 0, stream>>>(pooled, V0w, V0b, V1w, V1b, out);
}

// Round 7
// 755.463 us; speedup vs baseline: 1.0201x; 1.0201x over previous
//
#include <hip/hip_runtime.h>
#include <hip/hip_fp16.h>
#include <cstdint>

#define HD    128
#define OUTD  10
#define NG    512
#define KSTEPS 10

typedef unsigned short ushort_t;
typedef unsigned int   uint_t;
typedef unsigned char  uchar_t;

// bf16 helpers (stored as ushort; f32 accumulate everywhere)
__device__ __forceinline__ float bf_lo(uint_t u) { return __uint_as_float(u << 16); }
__device__ __forceinline__ float bf_hi(uint_t u) { return __uint_as_float(u & 0xFFFF0000u); }
__device__ __forceinline__ uint_t f2bf_rne(float f) {          // 16-bit result
    uint_t u = __float_as_uint(f);
    return (u + 0x7FFFu + ((u >> 16) & 1u)) >> 16;
}
__device__ __forceinline__ uint_t pack_bf2(float lo, float hi) {
    return f2bf_rne(lo) | (f2bf_rne(hi) << 16);
}

// ---------------------------------------------------------------------------
// 1) Collapse the two linear layers: Wc = W1@W2, bc = b1@W2 + b2
// ---------------------------------------------------------------------------
__global__ void wc_kernel(const float* __restrict__ W1, const float* __restrict__ b1,
                          const float* __restrict__ W2, const float* __restrict__ b2,
                          float* __restrict__ Wc, float* __restrict__ bc) {
    int idx = blockIdx.x * 256 + threadIdx.x;      // 0..16383
    int d = idx >> 7, j = idx & 127;
    float s = 0.f;
    for (int t = 0; t < HD; t++) s += W1[d * HD + t] * W2[t * HD + j];
    Wc[idx] = s;
    if (idx < HD) {
        float sb = b2[idx];
        for (int t = 0; t < HD; t++) sb += b1[t] * W2[t * HD + idx];
        bc[idx] = sb;
    }
}

// ---------------------------------------------------------------------------
// 2) h[n][j] = sum_d feat[d][n]*Wc[d][j] + bc[j] -> bf16 [N][128]
//    8x8 register-tiled GEMM: 128 nodes x 128 dims per block, operands
//    LDS-staged in 32-d chunks. 1 B of LDS operand per FMA (was 2 B with
//    the old 1-D mapping -> LDS-pipe-bound at 52 us). wv read carries a
//    4-way bank conflict (16 lanes @ stride 8 words, 1.58x) - accepted.
// ---------------------------------------------------------------------------
#define FNT 128                 // nodes per block
#define FDC 32                  // d-chunk
__global__ void __launch_bounds__(256) feat_kernel(
        const float* __restrict__ feat, const float* __restrict__ Wc,
        const float* __restrict__ bc, ushort_t* __restrict__ h, int N) {
    __shared__ float fch[FDC * FNT];          // [dd][n]
    __shared__ float wch[FDC * FNT];          // [dd][j]
    int t = threadIdx.x;
    int nb0 = blockIdx.x * FNT;
    int tj = t & 15, tn = t >> 4;             // 8 j x 8 n per thread
    int j0 = tj * 8, n0 = tn * 8;

    float acc[8][8];
    #pragma unroll
    for (int a = 0; a < 8; a++)
        #pragma unroll
        for (int b = 0; b < 8; b++) acc[a][b] = 0.f;

    for (int dc = 0; dc < HD; dc += FDC) {
        #pragma unroll
        for (int k = 0; k < (FDC * FNT) / 256; k++) {    // 16 iters
            int l = k * 256 + t;
            int dd = l >> 7, n = l & 127;
            int nn = nb0 + n;
            fch[l] = (nn < N) ? feat[(size_t)(dc + dd) * N + nn] : 0.f;
            wch[l] = Wc[(dc + dd) * HD + n];
        }
        __syncthreads();
        for (int dd = 0; dd < FDC; dd++) {
            const float* fr = &fch[dd * FNT + n0];
            const float* wr = &wch[dd * FNT + j0];
            float fv[8], wv[8];
            #pragma unroll
            for (int a = 0; a < 8; a++) { fv[a] = fr[a]; wv[a] = wr[a]; }
            #pragma unroll
            for (int a = 0; a < 8; a++)
                #pragma unroll
                for (int b = 0; b < 8; b++) acc[a][b] += fv[a] * wv[b];
        }
        __syncthreads();
    }

    float bv[8];
    #pragma unroll
    for (int b = 0; b < 8; b++) bv[b] = bc[j0 + b];
    #pragma unroll
    for (int a = 0; a < 8; a++) {
        int n = nb0 + n0 + a;
        if (n < N) {
            uint4 ov;
            ov.x = pack_bf2(acc[a][0] + bv[0], acc[a][1] + bv[1]);
            ov.y = pack_bf2(acc[a][2] + bv[2], acc[a][3] + bv[3]);
            ov.z = pack_bf2(acc[a][4] + bv[4], acc[a][5] + bv[5]);
            ov.w = pack_bf2(acc[a][6] + bv[6], acc[a][7] + bv[7]);
            *(uint4*)(h + (size_t)n * HD + j0) = ov;
        }
    }
}

// ---------------------------------------------------------------------------
// 3) CSR build via two-level bucket sort (NO global per-node atomics).
// ---------------------------------------------------------------------------

// S1: global bucket sizes (LDS hist, then one atomic per nonzero bucket/block)
__global__ void __launch_bounds__(256) bcount_kernel(
        const int* __restrict__ ei, int* __restrict__ gbhist, int E, int chunk) {
    __shared__ int lh[256];
    int b = blockIdx.x, t = threadIdx.x;
    lh[t] = 0;
    __syncthreads();
    int lo = b * chunk, hi = min(E, lo + chunk);
    for (int i = lo + t; i < hi; i += 256) atomicAdd(&lh[ei[E + i] >> 8], 1);
    __syncthreads();
    if (lh[t]) atomicAdd(&gbhist[t], lh[t]);
}

// S2: exclusive scan of bucket sizes -> bucket_base[0..NBK], bcursor init
__global__ void bscan_kernel(const int* __restrict__ gbhist, int* __restrict__ bucket_base,
                             int* __restrict__ bcursor, int NBK, int E) {
    __shared__ int sm[256];
    int t = threadIdx.x;
    int v = (t < NBK) ? gbhist[t] : 0;
    sm[t] = v;
    __syncthreads();
    for (int off = 1; off < 256; off <<= 1) {
        int u = (t >= off) ? sm[t - off] : 0;
        __syncthreads();
        sm[t] += u;
        __syncthreads();
    }
    int excl = sm[t] - v;
    if (t < NBK) { bucket_base[t] = excl; bcursor[t] = excl; }
    if (t == 0) bucket_base[NBK] = E;
}

// S3: scatter edges into bucket-ordered intermediate (rec + low-byte of dst).
__global__ void __launch_bounds__(256) bscatter_kernel(
        const int* __restrict__ ei, const float* __restrict__ ewt,
        int* __restrict__ bcursor, uint_t* __restrict__ rec_tmp,
        uchar_t* __restrict__ dlo_tmp, int E, int chunk) {
    __shared__ int lh[256];
    __shared__ int lcur[256];
    int b = blockIdx.x, t = threadIdx.x;
    lh[t] = 0;
    __syncthreads();
    int lo = b * chunk, hi = min(E, lo + chunk);
    for (int i = lo + t; i < hi; i += 256) atomicAdd(&lh[ei[E + i] >> 8], 1);
    __syncthreads();
    lcur[t] = lh[t] ? atomicAdd(&bcursor[t], lh[t]) : 0;
    __syncthreads();
    for (int i = lo + t; i < hi; i += 256) {
        int d = ei[E + i];
        int p = atomicAdd(&lcur[d >> 8], 1);
        rec_tmp[p] = ((uint_t)ei[i] << 16) |
                     (uint_t)__half_as_ushort(__float2half(ewt[i]));
        dlo_tmp[p] = (uchar_t)(d & 255);
    }
}

// S4: within-bucket counting sort by dst&255 (all in LDS); emit row_ptr+erec.
__global__ void __launch_bounds__(256) bsort_kernel(
        const uint_t* __restrict__ rec_tmp, const uchar_t* __restrict__ dlo_tmp,
        const int* __restrict__ bucket_base, int* __restrict__ row_ptr,
        uint_t* __restrict__ erec, int N, int E) {
    __shared__ int hist[256];
    __shared__ int scn[256];
    __shared__ int cur[256];
    int b = blockIdx.x, t = threadIdx.x;
    int lo = bucket_base[b], hi = bucket_base[b + 1];
    hist[t] = 0;
    __syncthreads();
    for (int i = lo + t; i < hi; i += 256) atomicAdd(&hist[dlo_tmp[i]], 1);
    __syncthreads();
    int v = hist[t];
    scn[t] = v;
    __syncthreads();
    for (int off = 1; off < 256; off <<= 1) {
        int u = (t >= off) ? scn[t - off] : 0;
        __syncthreads();
        scn[t] += u;
        __syncthreads();
    }
    int excl = lo + scn[t] - v;
    int node = (b << 8) + t;
    if (node < N) row_ptr[node] = excl;
    if (b == 0 && t == 0) row_ptr[N] = E;
    cur[t] = excl;
    __syncthreads();
    for (int i = lo + t; i < hi; i += 256) {
        int p = atomicAdd(&cur[dlo_tmp[i]], 1);
        erec[p] = rec_tmp[i];
    }
}

// ---------------------------------------------------------------------------
// 4) APPNP step (bf16 rows): wave per dst node; 4 groups x 16 lanes; each
//    group owns one edge, reads the 256B bf16 row as one uint4 per lane.
//    8x unroll + 8-record prefetch. Tail slots use clamped record 0
//    (src=0, w=0): cache-broadcast hits, ~free.
//    (R3: guards + nt loads regress. R6: degree-class perm is a null —
//    trip-count quantization is NOT the bottleneck.) f32 acc, bf16-RNE out.
// ---------------------------------------------------------------------------
__global__ void __launch_bounds__(256) prop_kernel(
        const ushort_t* __restrict__ xs, ushort_t* __restrict__ xd,
        const ushort_t* __restrict__ h, const int* __restrict__ row_ptr,
        const uint_t* __restrict__ erec, int N) {
    int wid = threadIdx.x >> 6, lane = threadIdx.x & 63;
    int node = blockIdx.x * 4 + wid;
    if (node >= N) return;
    int rs = row_ptr[node], re = row_ptr[node + 1];
    int grp = lane >> 4;        // edge slot 0..3
    int sub = lane & 15;        // dim slot: bf16 elems sub*8 .. sub*8+7

    float acc[8];
    #pragma unroll
    for (int i = 0; i < 8; i++) acc[i] = 0.f;

    uint_t p[8];
    #pragma unroll
    for (int u = 0; u < 8; u++) {
        int e = rs + grp + 4 * u;
        p[u] = (e < re) ? erec[e] : 0u;      // src=0, w=+0.0h
    }

    for (int base = rs; base < re; base += 32) {
        // prefetch next iteration's edge records
        uint_t q[8];
        #pragma unroll
        for (int u = 0; u < 8; u++) {
            int e = base + 32 + grp + 4 * u;
            q[u] = (e < re) ? erec[e] : 0u;
        }
        // 8 independent row gathers in flight (tail slots hit row 0, w=0)
        #pragma unroll
        for (int u = 0; u < 8; u++) {
            int   s = (int)(p[u] >> 16);
            float w = __half2float(__ushort_as_half((ushort_t)(p[u] & 0xFFFFu)));
            uint4 a = ((const uint4*)(xs + (size_t)s * HD))[sub];
            acc[0] += w * bf_lo(a.x); acc[1] += w * bf_hi(a.x);
            acc[2] += w * bf_lo(a.y); acc[3] += w * bf_hi(a.y);
            acc[4] += w * bf_lo(a.z); acc[5] += w * bf_hi(a.z);
            acc[6] += w * bf_lo(a.w); acc[7] += w * bf_hi(a.w);
        }
        #pragma unroll
        for (int u = 0; u < 8; u++) p[u] = q[u];
    }

    // reduce across the 4 edge groups
    #pragma unroll
    for (int off = 32; off >= 16; off >>= 1) {
        #pragma unroll
        for (int i = 0; i < 8; i++) acc[i] += __shfl_down(acc[i], off);
    }

    if (grp == 0) {
        uint4 hv = ((const uint4*)(h + (size_t)node * HD))[sub];
        float hf[8];
        hf[0] = bf_lo(hv.x); hf[1] = bf_hi(hv.x);
        hf[2] = bf_lo(hv.y); hf[3] = bf_hi(hv.y);
        hf[4] = bf_lo(hv.z); hf[5] = bf_hi(hv.z);
        hf[6] = bf_lo(hv.w); hf[7] = bf_hi(hv.w);
        float o[8];
        #pragma unroll
        for (int i = 0; i < 8; i++) o[i] = 0.9f * acc[i] + 0.1f * hf[i];
        uint4 ov;
        ov.x = pack_bf2(o[0], o[1]);
        ov.y = pack_bf2(o[2], o[3]);
        ov.z = pack_bf2(o[4], o[5]);
        ov.w = pack_bf2(o[6], o[7]);
        ((uint4*)(xd + (size_t)node * HD))[sub] = ov;
    }
}

// ---------------------------------------------------------------------------
// 5) Pool: batch is sorted -> running accumulator, atomic only on boundary.
// ---------------------------------------------------------------------------
#define POOL_CHUNK 128
__global__ void pool_kernel(const ushort_t* __restrict__ x, const int* __restrict__ batch,
                            float* __restrict__ pooled, int N) {
    int j = threadIdx.x;
    int n0 = blockIdx.x * POOL_CHUNK;
    if (n0 >= N) return;
    int n1 = min(n0 + POOL_CHUNK, N);
    int cur = batch[n0];
    float acc = 0.f;
    for (int n = n0; n < n1; n++) {
        int g = batch[n];
        if (g != cur) {
            atomicAdd(&pooled[cur * HD + j], acc);
            acc = 0.f; cur = g;
        }
        acc += __uint_as_float(((uint_t)x[(size_t)n * HD + j]) << 16);
    }
    atomicAdd(&pooled[cur * HD + j], acc);
}

// ---------------------------------------------------------------------------
// 6) Head: y = log_softmax(relu(pooled@V0w+V0b) @ V1w + V1b). Block per graph.
// ---------------------------------------------------------------------------
__global__ void head_kernel(const float* __restrict__ pooled, const float* __restrict__ V0w,
                            const float* __restrict__ V0b, const float* __restrict__ V1w,
                            const float* __restrict__ V1b, float* __restrict__ out) {
    __shared__ float prow[HD];
    __shared__ float y1[HD];
    __shared__ float y2[OUTD];
    __shared__ float lse;
    int g = blockIdx.x, j = threadIdx.x;
    prow[j] = pooled[g * HD + j];
    __syncthreads();
    float a = V0b[j];
    for (int d = 0; d < HD; d++) a += prow[d] * V0w[d * HD + j];
    y1[j] = a > 0.f ? a : 0.f;
    __syncthreads();
    if (j < OUTD) {
        float a2 = V1b[j];
        for (int t = 0; t < HD; t++) a2 += y1[t] * V1w[t * OUTD + j];
        y2[j] = a2;
    }
    __syncthreads();
    if (j == 0) {
        float m = y2[0];
        for (int o = 1; o < OUTD; o++) m = fmaxf(m, y2[o]);
        float s = 0.f;
        for (int o = 0; o < OUTD; o++) s += expf(y2[o] - m);
        lse = m + logf(s);
    }
    __syncthreads();
    if (j < OUTD) out[g * OUTD + j] = y2[j] - lse;
}

// ---------------------------------------------------------------------------
extern "C" void kernel_launch(void* const* d_in, const int* in_sizes, int n_in,
                              void* d_out, int out_size, void* d_ws, size_t ws_size,
                              hipStream_t stream) {
    const float* feat = (const float*)d_in[0];
    const float* ewt  = (const float*)d_in[1];
    const float* W1   = (const float*)d_in[2];
    const float* b1   = (const float*)d_in[3];
    const float* W2   = (const float*)d_in[4];
    const float* b2   = (const float*)d_in[5];
    const float* V0w  = (const float*)d_in[6];
    const float* V0b  = (const float*)d_in[7];
    const float* V1w  = (const float*)d_in[8];
    const float* V1b  = (const float*)d_in[9];
    const int*   ei   = (const int*)d_in[10];
    const int*   batch= (const int*)d_in[11];
    const int E = in_sizes[1];
    const int N = in_sizes[11];
    float* out = (float*)d_out;

    char* ws = (char*)d_ws;
    size_t off = 0;
    auto alloc = [&](size_t bytes) -> char* {
        char* p = ws + off;
        off = (off + bytes + 255) & ~(size_t)255;
        return p;
    };
    float*    Wc        = (float*)alloc((size_t)HD * HD * 4);
    float*    bc        = (float*)alloc((size_t)HD * 4);
    ushort_t* hb        = (ushort_t*)alloc((size_t)N * HD * 2);
    ushort_t* xA        = (ushort_t*)alloc((size_t)N * HD * 2);
    ushort_t* xB        = (ushort_t*)alloc((size_t)N * HD * 2);
    float*    pooled    = (float*)alloc((size_t)NG * HD * 4);
    int*      row_ptr   = (int*)alloc((size_t)(N + 1) * 4);
    int*      gbhist    = (int*)alloc((size_t)256 * 4);
    int*      bucket_b  = (int*)alloc((size_t)257 * 4);
    int*      bcursor   = (int*)alloc((size_t)256 * 4);
    uint_t*   rec_tmp   = (uint_t*)alloc((size_t)E * 4);
    uchar_t*  dlo_tmp   = (uchar_t*)alloc((size_t)E);
    uint_t*   erec      = (uint_t*)alloc((size_t)E * 4);
    (void)ws_size;

    hipMemsetAsync(gbhist, 0, (size_t)256 * 4, stream);
    hipMemsetAsync(pooled, 0, (size_t)NG * HD * 4, stream);

    const int NBK    = (N + 255) >> 8;          // dst buckets (<=256 for N<65536)
    const int SBLK   = 256;                     // edge scatter blocks
    const int chunk  = (E + SBLK - 1) / SBLK;   // edges per scatter block

    wc_kernel<<<64, 256, 0, stream>>>(W1, b1, W2, b2, Wc, bc);
    feat_kernel<<<(N + FNT - 1) / FNT, 256, 0, stream>>>(feat, Wc, bc, hb, N);
    bcount_kernel<<<SBLK, 256, 0, stream>>>(ei, gbhist, E, chunk);
    bscan_kernel<<<1, 256, 0, stream>>>(gbhist, bucket_b, bcursor, NBK, E);
    bscatter_kernel<<<SBLK, 256, 0, stream>>>(ei, ewt, bcursor, rec_tmp, dlo_tmp, E, chunk);
    bsort_kernel<<<NBK, 256, 0, stream>>>(rec_tmp, dlo_tmp, bucket_b, row_ptr, erec, N, E);

    const ushort_t* src = hb;
    ushort_t* dst = xA;
    for (int k = 0; k < KSTEPS; k++) {
        prop_kernel<<<(N + 3) / 4, 256, 0, stream>>>(src, dst, hb, row_ptr, erec, N);
        src = dst;
        dst = (dst == xA) ? xB : xA;
    }

    pool_kernel<<<(N + POOL_CHUNK - 1) / POOL_CHUNK, HD, 0, stream>>>(src, batch, pooled, N);
    head_kernel<<<NG, HD, 0, stream>>>(pooled, V0w, V0b, V1w, V1b, out);
}

// Round 8
// 735.598 us; speedup vs baseline: 1.0476x; 1.0270x over previous
//
#include <hip/hip_runtime.h>
#include <hip/hip_fp16.h>
#include <cstdint>

#define HD    128
#define OUTD  10
#define NG    512
#define KSTEPS 10

typedef unsigned short ushort_t;
typedef unsigned int   uint_t;
typedef unsigned char  uchar_t;

// bf16 helpers (stored as ushort; f32 accumulate everywhere)
__device__ __forceinline__ float bf_lo(uint_t u) { return __uint_as_float(u << 16); }
__device__ __forceinline__ float bf_hi(uint_t u) { return __uint_as_float(u & 0xFFFF0000u); }
__device__ __forceinline__ uint_t f2bf_rne(float f) {          // 16-bit result
    uint_t u = __float_as_uint(f);
    return (u + 0x7FFFu + ((u >> 16) & 1u)) >> 16;
}
__device__ __forceinline__ uint_t pack_bf2(float lo, float hi) {
    return f2bf_rne(lo) | (f2bf_rne(hi) << 16);
}

// ---------------------------------------------------------------------------
// 1) Collapse the two linear layers: Wc = W1@W2, bc = b1@W2 + b2
// ---------------------------------------------------------------------------
__global__ void wc_kernel(const float* __restrict__ W1, const float* __restrict__ b1,
                          const float* __restrict__ W2, const float* __restrict__ b2,
                          float* __restrict__ Wc, float* __restrict__ bc) {
    int idx = blockIdx.x * 256 + threadIdx.x;      // 0..16383
    int d = idx >> 7, j = idx & 127;
    float s = 0.f;
    for (int t = 0; t < HD; t++) s += W1[d * HD + t] * W2[t * HD + j];
    Wc[idx] = s;
    if (idx < HD) {
        float sb = b2[idx];
        for (int t = 0; t < HD; t++) sb += b1[t] * W2[t * HD + idx];
        bc[idx] = sb;
    }
}

// ---------------------------------------------------------------------------
// 2) h[n][j] = sum_d feat[d][n]*Wc[d][j] + bc[j] -> bf16 [N][128]
//    Register-tiled GEMM, 64 nodes x 128 dims per block (8j x 4n / thread).
//    R7 lesson: FNT=128 -> only 391 blocks -> 1 block/CU -> 14% occupancy,
//    latency-bound at 53 us. FNT=64 doubles grid to 782 (~3 blocks/CU,
//    24 KB LDS), keeping the register-tile operand ratio (~1.5 B LDS/FMA).
// ---------------------------------------------------------------------------
#define FNT 64                  // nodes per block
#define FDC 32                  // d-chunk
__global__ void __launch_bounds__(256) feat_kernel(
        const float* __restrict__ feat, const float* __restrict__ Wc,
        const float* __restrict__ bc, ushort_t* __restrict__ h, int N) {
    __shared__ float fch[FDC * FNT];          // [dd][n]  8 KB
    __shared__ float wch[FDC * HD];           // [dd][j] 16 KB
    int t = threadIdx.x;
    int nb0 = blockIdx.x * FNT;
    int tj = t & 15, tn = t >> 4;             // 16 j-groups x 16 n-groups
    int j0 = tj * 8, n0 = tn * 4;             // 8 j x 4 n per thread

    float acc[4][8];
    #pragma unroll
    for (int a = 0; a < 4; a++)
        #pragma unroll
        for (int b = 0; b < 8; b++) acc[a][b] = 0.f;

    for (int dc = 0; dc < HD; dc += FDC) {
        #pragma unroll
        for (int k = 0; k < (FDC * FNT) / 256; k++) {    // 8 iters
            int l = k * 256 + t;
            int dd = l >> 6, n = l & 63;
            int nn = nb0 + n;
            fch[l] = (nn < N) ? feat[(size_t)(dc + dd) * N + nn] : 0.f;
        }
        #pragma unroll
        for (int k = 0; k < (FDC * HD) / 256; k++) {     // 16 iters
            int l = k * 256 + t;
            int dd = l >> 7, j = l & 127;
            wch[l] = Wc[(dc + dd) * HD + j];
        }
        __syncthreads();
        for (int dd = 0; dd < FDC; dd++) {
            const float* fr = &fch[dd * FNT + n0];
            const float* wr = &wch[dd * HD + j0];
            float fv[4], wv[8];
            #pragma unroll
            for (int a = 0; a < 4; a++) fv[a] = fr[a];
            #pragma unroll
            for (int b = 0; b < 8; b++) wv[b] = wr[b];
            #pragma unroll
            for (int a = 0; a < 4; a++)
                #pragma unroll
                for (int b = 0; b < 8; b++) acc[a][b] += fv[a] * wv[b];
        }
        __syncthreads();
    }

    float bv[8];
    #pragma unroll
    for (int b = 0; b < 8; b++) bv[b] = bc[j0 + b];
    #pragma unroll
    for (int a = 0; a < 4; a++) {
        int n = nb0 + n0 + a;
        if (n < N) {
            uint4 ov;
            ov.x = pack_bf2(acc[a][0] + bv[0], acc[a][1] + bv[1]);
            ov.y = pack_bf2(acc[a][2] + bv[2], acc[a][3] + bv[3]);
            ov.z = pack_bf2(acc[a][4] + bv[4], acc[a][5] + bv[5]);
            ov.w = pack_bf2(acc[a][6] + bv[6], acc[a][7] + bv[7]);
            *(uint4*)(h + (size_t)n * HD + j0) = ov;
        }
    }
}

// ---------------------------------------------------------------------------
// 3) CSR build via two-level bucket sort (NO global per-node atomics).
// ---------------------------------------------------------------------------

// S1: global bucket sizes (LDS hist, then one atomic per nonzero bucket/block)
__global__ void __launch_bounds__(256) bcount_kernel(
        const int* __restrict__ ei, int* __restrict__ gbhist, int E, int chunk) {
    __shared__ int lh[256];
    int b = blockIdx.x, t = threadIdx.x;
    lh[t] = 0;
    __syncthreads();
    int lo = b * chunk, hi = min(E, lo + chunk);
    for (int i = lo + t; i < hi; i += 256) atomicAdd(&lh[ei[E + i] >> 8], 1);
    __syncthreads();
    if (lh[t]) atomicAdd(&gbhist[t], lh[t]);
}

// S2: exclusive scan of bucket sizes -> bucket_base[0..NBK], bcursor init
__global__ void bscan_kernel(const int* __restrict__ gbhist, int* __restrict__ bucket_base,
                             int* __restrict__ bcursor, int NBK, int E) {
    __shared__ int sm[256];
    int t = threadIdx.x;
    int v = (t < NBK) ? gbhist[t] : 0;
    sm[t] = v;
    __syncthreads();
    for (int off = 1; off < 256; off <<= 1) {
        int u = (t >= off) ? sm[t - off] : 0;
        __syncthreads();
        sm[t] += u;
        __syncthreads();
    }
    int excl = sm[t] - v;
    if (t < NBK) { bucket_base[t] = excl; bcursor[t] = excl; }
    if (t == 0) bucket_base[NBK] = E;
}

// S3: scatter edges into bucket-ordered intermediate (rec + low-byte of dst).
__global__ void __launch_bounds__(256) bscatter_kernel(
        const int* __restrict__ ei, const float* __restrict__ ewt,
        int* __restrict__ bcursor, uint_t* __restrict__ rec_tmp,
        uchar_t* __restrict__ dlo_tmp, int E, int chunk) {
    __shared__ int lh[256];
    __shared__ int lcur[256];
    int b = blockIdx.x, t = threadIdx.x;
    lh[t] = 0;
    __syncthreads();
    int lo = b * chunk, hi = min(E, lo + chunk);
    for (int i = lo + t; i < hi; i += 256) atomicAdd(&lh[ei[E + i] >> 8], 1);
    __syncthreads();
    lcur[t] = lh[t] ? atomicAdd(&bcursor[t], lh[t]) : 0;
    __syncthreads();
    for (int i = lo + t; i < hi; i += 256) {
        int d = ei[E + i];
        int p = atomicAdd(&lcur[d >> 8], 1);
        rec_tmp[p] = ((uint_t)ei[i] << 16) |
                     (uint_t)__half_as_ushort(__float2half(ewt[i]));
        dlo_tmp[p] = (uchar_t)(d & 255);
    }
}

// S4: within-bucket counting sort by dst&255 (all in LDS); emit row_ptr+erec.
__global__ void __launch_bounds__(256) bsort_kernel(
        const uint_t* __restrict__ rec_tmp, const uchar_t* __restrict__ dlo_tmp,
        const int* __restrict__ bucket_base, int* __restrict__ row_ptr,
        uint_t* __restrict__ erec, int N, int E) {
    __shared__ int hist[256];
    __shared__ int scn[256];
    __shared__ int cur[256];
    int b = blockIdx.x, t = threadIdx.x;
    int lo = bucket_base[b], hi = bucket_base[b + 1];
    hist[t] = 0;
    __syncthreads();
    for (int i = lo + t; i < hi; i += 256) atomicAdd(&hist[dlo_tmp[i]], 1);
    __syncthreads();
    int v = hist[t];
    scn[t] = v;
    __syncthreads();
    for (int off = 1; off < 256; off <<= 1) {
        int u = (t >= off) ? scn[t - off] : 0;
        __syncthreads();
        scn[t] += u;
        __syncthreads();
    }
    int excl = lo + scn[t] - v;
    int node = (b << 8) + t;
    if (node < N) row_ptr[node] = excl;
    if (b == 0 && t == 0) row_ptr[N] = E;
    cur[t] = excl;
    __syncthreads();
    for (int i = lo + t; i < hi; i += 256) {
        int p = atomicAdd(&cur[dlo_tmp[i]], 1);
        erec[p] = rec_tmp[i];
    }
}

// ---------------------------------------------------------------------------
// 4) APPNP step (bf16 rows): wave per dst node; 4 groups x 16 lanes; each
//    group owns one edge, reads the 256B bf16 row as one uint4 per lane.
//    8x unroll + 8-record prefetch. Tail slots use clamped record 0
//    (src=0, w=0): cache-broadcast hits, ~free.
//    (R3: guards + nt loads regress. R6: degree-class perm is a null —
//    trip-count quantization is NOT the bottleneck.) f32 acc, bf16-RNE out.
// ---------------------------------------------------------------------------
__global__ void __launch_bounds__(256) prop_kernel(
        const ushort_t* __restrict__ xs, ushort_t* __restrict__ xd,
        const ushort_t* __restrict__ h, const int* __restrict__ row_ptr,
        const uint_t* __restrict__ erec, int N) {
    int wid = threadIdx.x >> 6, lane = threadIdx.x & 63;
    int node = blockIdx.x * 4 + wid;
    if (node >= N) return;
    int rs = row_ptr[node], re = row_ptr[node + 1];
    int grp = lane >> 4;        // edge slot 0..3
    int sub = lane & 15;        // dim slot: bf16 elems sub*8 .. sub*8+7

    float acc[8];
    #pragma unroll
    for (int i = 0; i < 8; i++) acc[i] = 0.f;

    uint_t p[8];
    #pragma unroll
    for (int u = 0; u < 8; u++) {
        int e = rs + grp + 4 * u;
        p[u] = (e < re) ? erec[e] : 0u;      // src=0, w=+0.0h
    }

    for (int base = rs; base < re; base += 32) {
        // prefetch next iteration's edge records
        uint_t q[8];
        #pragma unroll
        for (int u = 0; u < 8; u++) {
            int e = base + 32 + grp + 4 * u;
            q[u] = (e < re) ? erec[e] : 0u;
        }
        // 8 independent row gathers in flight (tail slots hit row 0, w=0)
        #pragma unroll
        for (int u = 0; u < 8; u++) {
            int   s = (int)(p[u] >> 16);
            float w = __half2float(__ushort_as_half((ushort_t)(p[u] & 0xFFFFu)));
            uint4 a = ((const uint4*)(xs + (size_t)s * HD))[sub];
            acc[0] += w * bf_lo(a.x); acc[1] += w * bf_hi(a.x);
            acc[2] += w * bf_lo(a.y); acc[3] += w * bf_hi(a.y);
            acc[4] += w * bf_lo(a.z); acc[5] += w * bf_hi(a.z);
            acc[6] += w * bf_lo(a.w); acc[7] += w * bf_hi(a.w);
        }
        #pragma unroll
        for (int u = 0; u < 8; u++) p[u] = q[u];
    }

    // reduce across the 4 edge groups
    #pragma unroll
    for (int off = 32; off >= 16; off >>= 1) {
        #pragma unroll
        for (int i = 0; i < 8; i++) acc[i] += __shfl_down(acc[i], off);
    }

    if (grp == 0) {
        uint4 hv = ((const uint4*)(h + (size_t)node * HD))[sub];
        float hf[8];
        hf[0] = bf_lo(hv.x); hf[1] = bf_hi(hv.x);
        hf[2] = bf_lo(hv.y); hf[3] = bf_hi(hv.y);
        hf[4] = bf_lo(hv.z); hf[5] = bf_hi(hv.z);
        hf[6] = bf_lo(hv.w); hf[7] = bf_hi(hv.w);
        float o[8];
        #pragma unroll
        for (int i = 0; i < 8; i++) o[i] = 0.9f * acc[i] + 0.1f * hf[i];
        uint4 ov;
        ov.x = pack_bf2(o[0], o[1]);
        ov.y = pack_bf2(o[2], o[3]);
        ov.z = pack_bf2(o[4], o[5]);
        ov.w = pack_bf2(o[6], o[7]);
        ((uint4*)(xd + (size_t)node * HD))[sub] = ov;
    }
}

// ---------------------------------------------------------------------------
// 5) Pool: batch is sorted -> running accumulator, atomic only on boundary.
// ---------------------------------------------------------------------------
#define POOL_CHUNK 128
__global__ void pool_kernel(const ushort_t* __restrict__ x, const int* __restrict__ batch,
                            float* __restrict__ pooled, int N) {
    int j = threadIdx.x;
    int n0 = blockIdx.x * POOL_CHUNK;
    if (n0 >= N) return;
    int n1 = min(n0 + POOL_CHUNK, N);
    int cur = batch[n0];
    float acc = 0.f;
    for (int n = n0; n < n1; n++) {
        int g = batch[n];
        if (g != cur) {
            atomicAdd(&pooled[cur * HD + j], acc);
            acc = 0.f; cur = g;
        }
        acc += __uint_as_float(((uint_t)x[(size_t)n * HD + j]) << 16);
    }
    atomicAdd(&pooled[cur * HD + j], acc);
}

// ---------------------------------------------------------------------------
// 6) Head: y = log_softmax(relu(pooled@V0w+V0b) @ V1w + V1b). Block per graph.
// ---------------------------------------------------------------------------
__global__ void head_kernel(const float* __restrict__ pooled, const float* __restrict__ V0w,
                            const float* __restrict__ V0b, const float* __restrict__ V1w,
                            const float* __restrict__ V1b, float* __restrict__ out) {
    __shared__ float prow[HD];
    __shared__ float y1[HD];
    __shared__ float y2[OUTD];
    __shared__ float lse;
    int g = blockIdx.x, j = threadIdx.x;
    prow[j] = pooled[g * HD + j];
    __syncthreads();
    float a = V0b[j];
    for (int d = 0; d < HD; d++) a += prow[d] * V0w[d * HD + j];
    y1[j] = a > 0.f ? a : 0.f;
    __syncthreads();
    if (j < OUTD) {
        float a2 = V1b[j];
        for (int t = 0; t < HD; t++) a2 += y1[t] * V1w[t * OUTD + j];
        y2[j] = a2;
    }
    __syncthreads();
    if (j == 0) {
        float m = y2[0];
        for (int o = 1; o < OUTD; o++) m = fmaxf(m, y2[o]);
        float s = 0.f;
        for (int o = 0; o < OUTD; o++) s += expf(y2[o] - m);
        lse = m + logf(s);
    }
    __syncthreads();
    if (j < OUTD) out[g * OUTD + j] = y2[j] - lse;
}

// ---------------------------------------------------------------------------
extern "C" void kernel_launch(void* const* d_in, const int* in_sizes, int n_in,
                              void* d_out, int out_size, void* d_ws, size_t ws_size,
                              hipStream_t stream) {
    const float* feat = (const float*)d_in[0];
    const float* ewt  = (const float*)d_in[1];
    const float* W1   = (const float*)d_in[2];
    const float* b1   = (const float*)d_in[3];
    const float* W2   = (const float*)d_in[4];
    const float* b2   = (const float*)d_in[5];
    const float* V0w  = (const float*)d_in[6];
    const float* V0b  = (const float*)d_in[7];
    const float* V1w  = (const float*)d_in[8];
    const float* V1b  = (const float*)d_in[9];
    const int*   ei   = (const int*)d_in[10];
    const int*   batch= (const int*)d_in[11];
    const int E = in_sizes[1];
    const int N = in_sizes[11];
    float* out = (float*)d_out;

    char* ws = (char*)d_ws;
    size_t off = 0;
    auto alloc = [&](size_t bytes) -> char* {
        char* p = ws + off;
        off = (off + bytes + 255) & ~(size_t)255;
        return p;
    };
    float*    Wc        = (float*)alloc((size_t)HD * HD * 4);
    float*    bc        = (float*)alloc((size_t)HD * 4);
    ushort_t* hb        = (ushort_t*)alloc((size_t)N * HD * 2);
    ushort_t* xA        = (ushort_t*)alloc((size_t)N * HD * 2);
    ushort_t* xB        = (ushort_t*)alloc((size_t)N * HD * 2);
    float*    pooled    = (float*)alloc((size_t)NG * HD * 4);
    int*      row_ptr   = (int*)alloc((size_t)(N + 1) * 4);
    int*      gbhist    = (int*)alloc((size_t)256 * 4);
    int*      bucket_b  = (int*)alloc((size_t)257 * 4);
    int*      bcursor   = (int*)alloc((size_t)256 * 4);
    uint_t*   rec_tmp   = (uint_t*)alloc((size_t)E * 4);
    uchar_t*  dlo_tmp   = (uchar_t*)alloc((size_t)E);
    uint_t*   erec      = (uint_t*)alloc((size_t)E * 4);
    (void)ws_size;

    hipMemsetAsync(gbhist, 0, (size_t)256 * 4, stream);
    hipMemsetAsync(pooled, 0, (size_t)NG * HD * 4, stream);

    const int NBK    = (N + 255) >> 8;          // dst buckets (<=256 for N<65536)
    const int SBLK   = 256;                     // edge scatter blocks
    const int chunk  = (E + SBLK - 1) / SBLK;   // edges per scatter block

    wc_kernel<<<64, 256, 0, stream>>>(W1, b1, W2, b2, Wc, bc);
    feat_kernel<<<(N + FNT - 1) / FNT, 256, 0, stream>>>(feat, Wc, bc, hb, N);
    bcount_kernel<<<SBLK, 256, 0, stream>>>(ei, gbhist, E, chunk);
    bscan_kernel<<<1, 256, 0, stream>>>(gbhist, bucket_b, bcursor, NBK, E);
    bscatter_kernel<<<SBLK, 256, 0, stream>>>(ei, ewt, bcursor, rec_tmp, dlo_tmp, E, chunk);
    bsort_kernel<<<NBK, 256, 0, stream>>>(rec_tmp, dlo_tmp, bucket_b, row_ptr, erec, N, E);

    const ushort_t* src = hb;
    ushort_t* dst = xA;
    for (int k = 0; k < KSTEPS; k++) {
        prop_kernel<<<(N + 3) / 4, 256, 0, stream>>>(src, dst, hb, row_ptr, erec, N);
        src = dst;
        dst = (dst == xA) ? xB : xA;
    }

    pool_kernel<<<(N + POOL_CHUNK - 1) / POOL_CHUNK, HD, 0, stream>>>(src, batch, pooled, N);
    head_kernel<<<NG, HD, 0, stream>>>(pooled, V0w, V0b, V1w, V1b, out);
}